// Round 3
// baseline (113.808 us; speedup 1.0000x reference)
//
#include <hip/hip_runtime.h>

// MpMaxPoolingMatch: out[b,t,m] = tanh( max_s sum_d lt[b,t,d]*km[m,d]*rt[b,s,d] )
// B=32, T=256, D=512, MP=20.
// R13: kill the two stall sources R12's counters exposed (MfmaUtil 17%, 58% idle):
//  1) cast_rt wrote rtf on XCD bid%8 but match reads it on XCD b%8 (mismatched) ->
//     every B read was cross-XCD (LLC/HBM ~500-900cy), outrunning the 3-step ring
//     lead. FETCH_SIZE 6.4->10.5MB corroborated. Fix: XCD-aligned cast mapping
//     (b = (bid&7) + 8*(bid>>3 & 3)) so rtf is L2-local (~200cy) to its consumer.
//  2) mk8 glued two non-adjacent 16B loads into each i32x8 (~256 v_movs/wave,
//     VALUBusy 24.6%). Fix: rtf tile is now 32B-CONTIGUOUS per lane
//     ([b][kk*16+g][lane][32B]) -> bv is ONE i32x8 global load (2 adjacent
//     dwordx4, no movs); Ash stride 33->34 makes A-frag 32B-aligned -> av is ONE
//     i32x8 LDS read (2x ds_read_b128, conflict-free, LDS still 35.8KB).
// Same MFMA byte order as R10-R12 (bitwise-identical math), same XCD swizzle,
// same 4-slot/lead-3 VGPR ring, same epilogue.

constexpr int TT = 256;   // T
constexpr int DD = 512;   // D
constexpr int NM = 20;    // MP
constexpr int NB = 32;    // B
constexpr int BM = 64;    // t-tile

typedef float f32x4 __attribute__((ext_vector_type(4)));
typedef int   i32x8 __attribute__((ext_vector_type(8)));

__device__ __forceinline__ unsigned pack_bf16(float lo, float hi) {
    unsigned ulo = __builtin_bit_cast(unsigned, lo);
    unsigned uhi = __builtin_bit_cast(unsigned, hi);
    return (ulo >> 16) | (uhi & 0xFFFF0000u);
}

// 4 fp32 -> 4 fp8 (e4m3, packed dword)
__device__ __forceinline__ unsigned pk4_fp8(float a, float b, float c, float d) {
    unsigned r = __builtin_amdgcn_cvt_pk_fp8_f32(a, b, 0, false);
    return __builtin_amdgcn_cvt_pk_fp8_f32(c, d, r, true);
}

// ---------------- Phase 1: rt fp32 -> fp8, 32B-contiguous lane tiles, XCD-aligned ----
// rtf layout: 32B element e = (b*4096 + (kk*16+g)*64 + lane):
//   holds rt[b][s = g*16 + (lane&15)][d = kk*128 + (lane>>4)*32 .. +32] as fp8.
__global__ __launch_bounds__(256)
void cast_rt(const float* __restrict__ rt, unsigned char* __restrict__ rtf)
{
    const int bid = (int)blockIdx.x;       // 0..511
    const int c8  = bid & 7;               // this block's XCD (flat%8)
    const int i   = bid >> 3;              // 0..63
    const int b   = c8 + 8 * (i & 3);      // b%8 == c8 == consumer XCD
    const int sub = i >> 2;                // 0..15
    const int tid = threadIdx.x;
    const int lane = tid & 63;
    const int u6  = sub * 4 + (tid >> 6);  // 0..63 == kk*16 + g
    const int s   = (u6 & 15) * 16 + (lane & 15);
    const int d0  = (u6 >> 4) * 128 + (lane >> 4) * 32;

    const float* p = rt + ((size_t)b * TT + s) * DD + d0;
    float4 x0 = *(const float4*)p;
    float4 x1 = *(const float4*)(p + 4);
    float4 x2 = *(const float4*)(p + 8);
    float4 x3 = *(const float4*)(p + 12);
    float4 x4 = *(const float4*)(p + 16);
    float4 x5 = *(const float4*)(p + 20);
    float4 x6 = *(const float4*)(p + 24);
    float4 x7 = *(const float4*)(p + 28);
    uint4 w0, w1;
    w0.x = pk4_fp8(x0.x, x0.y, x0.z, x0.w);
    w0.y = pk4_fp8(x1.x, x1.y, x1.z, x1.w);
    w0.z = pk4_fp8(x2.x, x2.y, x2.z, x2.w);
    w0.w = pk4_fp8(x3.x, x3.y, x3.z, x3.w);
    w1.x = pk4_fp8(x4.x, x4.y, x4.z, x4.w);
    w1.y = pk4_fp8(x5.x, x5.y, x5.z, x5.w);
    w1.z = pk4_fp8(x6.x, x6.y, x6.z, x6.w);
    w1.w = pk4_fp8(x7.x, x7.y, x7.z, x7.w);
    unsigned char* dst = rtf + ((size_t)b * 4096 + (size_t)u6 * 64 + lane) * 32;
    *(uint4*)dst        = w0;
    *(uint4*)(dst + 16) = w1;
}

// ---------------- Main: 64t x 256s, MX fp8 K=128, B in VGPR ring ----------------
__global__ __launch_bounds__(256, 3)
void mp_match_mx(const float* __restrict__ lt, const unsigned char* __restrict__ rtf,
                 const float* __restrict__ km, float* __restrict__ out)
{
    // stride 34 (even) -> every A-fragment (2 adjacent uint4) is 32B-aligned;
    // bank math: read bank_start = 8*(l15+l4) mod 32, write = (8r+4cc) mod 32 ->
    // both hit the 1KB/step LDS minimum, no extra conflicts.
    __shared__ __attribute__((aligned(32))) uint4 Ash[BM * 34];   // 34.8 KB
    __shared__ __attribute__((aligned(16))) float maxbuf[4][BM];  // 1 KB

    // XCD swizzle: flat%8 == XCD; b%8 == XCD.
    const int f  = blockIdx.x;           // 0..2559
    const int c8 = f & 7;
    const int i  = f >> 3;               // 0..319
    const int b  = c8 + 8 * (i / 80);    // 0..31
    const int j  = i % 80;
    const int m  = j >> 2;               // 0..19
    const int t0 = (j & 3) * BM;         // 0,64,128,192

    const int tid  = threadIdx.x;
    const int w    = tid >> 6;           // wave id = s-quarter owner
    const int lane = tid & 63;
    const int l15  = lane & 15;
    const int l4   = lane >> 4;

    const float* ltB = lt + ((size_t)b * TT + t0) * DD;
    const float* kmp = km + (size_t)m * DD;
    // step u = kk*4+q: element index (kk*16 + q*4 + w)*64 + lane = 4u*64 + w*64 + lane
    // -> byte offset u*8192 from rtB0. One 32B contiguous load per step.
    const unsigned char* rtB0 = rtf + (size_t)b * 131072 + (size_t)(w * 64 + lane) * 32;

    i32x8 ring[4];
    auto loadB = [&](int u) {
        ring[u & 3] = *(const i32x8*)(rtB0 + u * 8192);
    };

    // 3-deep prologue: in flight under the whole A conversion.
    loadB(0); loadB(1); loadB(2);

    // ---- A staging: thread -> chunk-col cc (d = cc*16..+16), rows r0..r0+8.
    // Reads lt fp32 directly (2KB contiguous per row per wave), fuses *km + fp8.
    const int cc = tid & 31, r0 = (tid >> 5) * 8;
    const float4 kA = *(const float4*)(kmp + cc * 16);
    const float4 kB = *(const float4*)(kmp + cc * 16 + 4);
    const float4 kC = *(const float4*)(kmp + cc * 16 + 8);
    const float4 kD = *(const float4*)(kmp + cc * 16 + 12);
#pragma unroll
    for (int r = 0; r < 8; ++r) {
        const float* src = ltB + (size_t)(r0 + r) * DD + cc * 16;
        float4 x0 = *(const float4*)src;
        float4 x1 = *(const float4*)(src + 4);
        float4 x2 = *(const float4*)(src + 8);
        float4 x3 = *(const float4*)(src + 12);
        uint4 o;
        o.x = pk4_fp8(x0.x * kA.x, x0.y * kA.y, x0.z * kA.z, x0.w * kA.w);
        o.y = pk4_fp8(x1.x * kB.x, x1.y * kB.y, x1.z * kB.z, x1.w * kB.w);
        o.z = pk4_fp8(x2.x * kC.x, x2.y * kC.y, x2.z * kC.z, x2.w * kC.w);
        o.w = pk4_fp8(x3.x * kD.x, x3.y * kD.y, x3.z * kD.z, x3.w * kD.w);
        Ash[(r0 + r) * 34 + cc] = o;
    }
    __syncthreads();   // the ONLY pre-epilogue barrier

    f32x4 acc[4][4] = {};   // [ii][q]: t = t0+ii*16+..., s = q*64 + w*16 + ...
    i32x8 av[4];

#pragma unroll
    for (int u = 0; u < 16; ++u) {
        const int kk = u >> 2, q = u & 3;
        if (u + 3 < 16) loadB(u + 3);   // ring WAR keeps this honest; lead = 3 steps
        if (q == 0) {
            // A frags for this kk: row = ii*16 + l15, 32B at chunk kk*8 + l4*2.
#pragma unroll
            for (int ii = 0; ii < 4; ++ii)
                av[ii] = *(const i32x8*)&Ash[(ii * 16 + l15) * 34 + kk * 8 + l4 * 2];
        }
        const i32x8 bv = ring[u & 3];
#pragma unroll
        for (int ii = 0; ii < 4; ++ii)
            acc[ii][q] = __builtin_amdgcn_mfma_scale_f32_16x16x128_f8f6f4(
                av[ii], bv, acc[ii][q], 0, 0, 0, 127, 0, 127);  // fmt=fp8, scales=1.0
    }

    // ---- Epilogue: max over s. C layout: col(s)=lane&15, row(t)=(lane>>4)*4+reg.
#pragma unroll
    for (int ii = 0; ii < 4; ++ii) {
        f32x4 v = acc[ii][0];
#pragma unroll
        for (int q = 1; q < 4; ++q) {
            v.x = fmaxf(v.x, acc[ii][q].x);
            v.y = fmaxf(v.y, acc[ii][q].y);
            v.z = fmaxf(v.z, acc[ii][q].z);
            v.w = fmaxf(v.w, acc[ii][q].w);
        }
#pragma unroll
        for (int off = 1; off < 16; off <<= 1) {
            v.x = fmaxf(v.x, __shfl_xor(v.x, off, 64));
            v.y = fmaxf(v.y, __shfl_xor(v.y, off, 64));
            v.z = fmaxf(v.z, __shfl_xor(v.z, off, 64));
            v.w = fmaxf(v.w, __shfl_xor(v.w, off, 64));
        }
        if (l15 == 0)
            *(f32x4*)&maxbuf[w][ii * 16 + l4 * 4] = v;
    }
    __syncthreads();
    if (tid < BM) {
        float v = fmaxf(fmaxf(maxbuf[0][tid], maxbuf[1][tid]),
                        fmaxf(maxbuf[2][tid], maxbuf[3][tid]));
        out[((size_t)b * TT + t0 + tid) * NM + m] = tanhf(v);
    }
}

// ---------------- R1 fallback (no workspace): bf16 MFMA, fp32 register staging ----------------
typedef short bf16x8 __attribute__((ext_vector_type(8)));

__global__ __launch_bounds__(256, 2)
void mp_match_kernel(const float* __restrict__ lt, const float* __restrict__ rt,
                     const float* __restrict__ km, float* __restrict__ out)
{
    __shared__ __attribute__((aligned(16))) unsigned short Ash[2][4][128][8];
    __shared__ __attribute__((aligned(16))) unsigned short Bsh2[2][4][256][8];
    __shared__ __attribute__((aligned(16))) float maxbuf[2][128];

    const int ttile = blockIdx.x, m = blockIdx.y, b = blockIdx.z;
    const int t0 = ttile * 128;
    const int tid = threadIdx.x, wave = tid >> 6, lane = tid & 63;
    const int l15 = lane & 15, l4 = lane >> 4;
    const int wt = (wave & 1) * 64, wsi = wave >> 1;

    const float* ltp = lt + ((size_t)b * TT + t0) * DD;
    const float* rtp = rt + (size_t)b * TT * DD;
    const float* kmp = km + (size_t)m * DD;
    const int a_t = tid >> 1, a_h = tid & 1;

    f32x4 acc[4][8] = {};

    auto stage = [&](int kk, int buf) {
        const int d0 = kk * 32;
        const float* ap = ltp + (size_t)a_t * DD + d0 + a_h * 16;
        const float* kp = kmp + d0 + a_h * 16;
#pragma unroll
        for (int q = 0; q < 2; ++q) {
            float4 x0 = *(const float4*)(ap + q * 8);
            float4 x1 = *(const float4*)(ap + q * 8 + 4);
            float4 k0 = *(const float4*)(kp + q * 8);
            float4 k1 = *(const float4*)(kp + q * 8 + 4);
            uint4 wv;
            wv.x = pack_bf16(x0.x * k0.x, x0.y * k0.y);
            wv.y = pack_bf16(x0.z * k0.z, x0.w * k0.w);
            wv.z = pack_bf16(x1.x * k1.x, x1.y * k1.y);
            wv.w = pack_bf16(x1.z * k1.z, x1.w * k1.w);
            *(uint4*)&Ash[buf][a_h * 2 + q][a_t][0] = wv;
        }
        const float* bp = rtp + (size_t)tid * DD + d0;
#pragma unroll
        for (int p = 0; p < 4; ++p) {
            float4 y0 = *(const float4*)(bp + p * 8);
            float4 y1 = *(const float4*)(bp + p * 8 + 4);
            uint4 wv;
            wv.x = pack_bf16(y0.x, y0.y);
            wv.y = pack_bf16(y0.z, y0.w);
            wv.z = pack_bf16(y1.x, y1.y);
            wv.w = pack_bf16(y1.z, y1.w);
            *(uint4*)&Bsh2[buf][p][tid][0] = wv;
        }
    };

    stage(0, 0);
    for (int kk = 0; kk < 16; ++kk) {
        const int buf = kk & 1;
        __syncthreads();
        bf16x8 af[4], bfv[8];
#pragma unroll
        for (int i2 = 0; i2 < 4; ++i2)
            af[i2] = *(const bf16x8*)&Ash[buf][l4][wt + i2 * 16 + l15][0];
#pragma unroll
        for (int j2 = 0; j2 < 8; ++j2)
            bfv[j2] = *(const bf16x8*)&Bsh2[buf][l4][wsi * 128 + j2 * 16 + l15][0];
        if (kk + 1 < 16) stage(kk + 1, buf ^ 1);
#pragma unroll
        for (int i2 = 0; i2 < 4; ++i2)
#pragma unroll
            for (int j2 = 0; j2 < 8; ++j2)
                acc[i2][j2] = __builtin_amdgcn_mfma_f32_16x16x32_bf16(af[i2], bfv[j2], acc[i2][j2], 0, 0, 0);
    }
#pragma unroll
    for (int i2 = 0; i2 < 4; ++i2) {
        f32x4 v = acc[i2][0];
#pragma unroll
        for (int j2 = 1; j2 < 8; ++j2) {
            v.x = fmaxf(v.x, acc[i2][j2].x); v.y = fmaxf(v.y, acc[i2][j2].y);
            v.z = fmaxf(v.z, acc[i2][j2].z); v.w = fmaxf(v.w, acc[i2][j2].w);
        }
#pragma unroll
        for (int off = 1; off < 16; off <<= 1) {
            v.x = fmaxf(v.x, __shfl_xor(v.x, off, 64));
            v.y = fmaxf(v.y, __shfl_xor(v.y, off, 64));
            v.z = fmaxf(v.z, __shfl_xor(v.z, off, 64));
            v.w = fmaxf(v.w, __shfl_xor(v.w, off, 64));
        }
        if (l15 == 0) *(f32x4*)&maxbuf[wsi][wt + i2 * 16 + l4 * 4] = v;
    }
    __syncthreads();
    if (tid < 128) {
        float v = fmaxf(maxbuf[0][tid], maxbuf[1][tid]);
        out[((size_t)b * TT + t0 + tid) * NM + m] = tanhf(v);
    }
}

extern "C" void kernel_launch(void* const* d_in, const int* in_sizes, int n_in,
                              void* d_out, int out_size, void* d_ws, size_t ws_size,
                              hipStream_t stream) {
    const float* lt  = (const float*)d_in[0];   // (32,256,512) fp32
    const float* rt  = (const float*)d_in[1];   // (32,256,512) fp32
    const float* km  = (const float*)d_in[2];   // (20,512) fp32
    float*       out = (float*)d_out;           // (32,256,20) fp32

    const size_t elems = (size_t)NB * TT * DD;  // 4,194,304
    const size_t rtfB  = elems;                 // 4.19 MB fp8 (tiled)

    if (ws_size >= rtfB) {
        unsigned char* rtf = (unsigned char*)d_ws;
        cast_rt<<<512, 256, 0, stream>>>(rt, rtf);           // 32 elem/thread, XCD-aligned
        mp_match_mx<<<2560, 256, 0, stream>>>(lt, rtf, km, out);
    } else {
        mp_match_kernel<<<dim3(2, NM, NB), 256, 0, stream>>>(lt, rt, km, out);
    }
}